// Round 7
// baseline (1141.152 us; speedup 1.0000x reference)
//
#include <hip/hip_runtime.h>
#include <hip/hip_bf16.h>
#include <cstdint>
#include <cstddef>

typedef unsigned short u16;
typedef _Float16 f16;
typedef f16 f16x8 __attribute__((ext_vector_type(8)));
typedef float f32x4 __attribute__((ext_vector_type(4)));

static __device__ __forceinline__ u16 f2h(float f) {
    f16 h = (f16)f;
    return *reinterpret_cast<u16*>(&h);
}
static __device__ __forceinline__ float h2f(u16 u) {
    f16 h = *reinterpret_cast<f16*>(&u);
    return (float)h;
}

// async global->LDS, 16B per lane; LDS dest = wave-uniform base + lane*16
#define GLL(g, l) __builtin_amdgcn_global_load_lds(                    \
    (const __attribute__((address_space(1))) void*)(g),                \
    (__attribute__((address_space(3))) void*)(l), 16, 0, 0)

#define BARR() __builtin_amdgcn_s_barrier()
#define VMCNT(n) { asm volatile("s_waitcnt vmcnt(" #n ")" ::: "memory"); \
                   __builtin_amdgcn_sched_barrier(0); }

// bijective XCD swizzle (all grids % 8 == 0)
static __device__ __forceinline__ int xcd_swz(int fid, int nwg) {
    const int q = nwg >> 3;
    return (fid & 7) * q + (fid >> 3);
}

#define TDIR (32ull * 512 * 1024)

// ======================= 8-phase 256x256 GEMM core =======================
// halftile = 128 rows x 64 u16 (16 KB). LDS layout: [buf(2)][half(2)] x 8192 u16.
// Swizzle: within halftile, byte col ^= ((row&12)<<3)  (4-way bank spread,
// applied to GLOBAL source at stage and to ds_read addr; LDS dest stays linear).

static __device__ __forceinline__ void stage_ht(const u16* __restrict__ src, int ld,
                                                u16* ldsHalf, int t) {
    #pragma unroll
    for (int s = 0; s < 2; ++s) {
        const int o = s * 8192 + t * 16;               // byte offset in halftile
        const int row = o >> 7;
        const int scolb = (o & 127) ^ ((row & 12) << 3);
        GLL(src + (size_t)row * ld + (scolb >> 1),
            ldsHalf + s * 4096 + (t >> 6) * 512);      // wave-uniform base
    }
}

template<int HH, bool BL>
static __device__ __forceinline__ void ph_read(const u16* cA, const u16* cB,
                                               int lr, int ce, int brb,
                                               f16x8 a[4], f16x8 b[4]) {
    #pragma unroll
    for (int i = 0; i < 4; ++i)
        a[i] = *reinterpret_cast<const f16x8*>(&cA[((HH * 4 + i) * 16 + lr) * 64 + ce]);
    if (BL) {
        #pragma unroll
        for (int j = 0; j < 4; ++j)
            b[j] = *reinterpret_cast<const f16x8*>(&cB[(brb + j * 16 + lr) * 64 + ce]);
    }
}

template<int HH>
static __device__ __forceinline__ void ph_mfma(const f16x8 a[4], const f16x8 b[4],
                                               f32x4 acc[8][4]) {
    asm volatile("s_waitcnt lgkmcnt(0)" ::: "memory");
    __builtin_amdgcn_sched_barrier(0);
    __builtin_amdgcn_s_setprio(1);
    #pragma unroll
    for (int i = 0; i < 4; ++i)
        #pragma unroll
        for (int j = 0; j < 4; ++j)
            acc[HH * 4 + i][j] =
                __builtin_amdgcn_mfma_f32_16x16x32_f16(a[i], b[j], acc[HH * 4 + i][j], 0, 0, 0);
    __builtin_amdgcn_s_setprio(0);
}

#define PHASE(HH, CE, BL, STAGE, VMW)              \
    { f16x8 a[4];                                  \
      ph_read<HH, BL>(cA, cB, lr, CE, brb, a, b);  \
      STAGE;                                       \
      VMW                                          \
      BARR();                                      \
      ph_mfma<HH>(a, b, acc);                      \
      BARR(); }

// C[256x256] = concat(a1,a2)[M x K] @ bt[N x K]^T ; K % 128 == 0, ka1 % 64 == 0.
// NOTE: prefetches read up to 128 u16 past [K] per row (never consumed) — callers
// guarantee those addresses stay inside the workspace.
static __device__ __forceinline__ void gemm256(const u16* __restrict__ a1, int lda1, int ka1,
                                               const u16* __restrict__ a2, int lda2,
                                               const u16* __restrict__ bt, int ldb,
                                               int K, int m0, int n0,
                                               u16* sA, u16* sB, f32x4 acc[8][4])
{
    const int t = threadIdx.x;
    const int lane = t & 63, wave = t >> 6;
    const int wm = wave >> 2, wn = wave & 3;
    const int lr = lane & 15, hi8 = (lane >> 4) << 3;
    const int brb = (wn & 1) << 6;
    const int ce0 = hi8 ^ ((lr & 12) << 2);   // u16 col, kk=0 (swizzled)
    const int ce1 = ce0 ^ 32;                 // kk=1
    const u16* A0 = sA + wm * 8192;           // buf0, my A-half
    const u16* A1h = sA + (2 + wm) * 8192;    // buf1
    const u16* B0 = sB + (wn >> 1) * 8192;
    const u16* B1h = sB + (2 + (wn >> 1)) * 8192;

    auto stA = [&](int kt, int h) {
        const int kcol = kt << 6;
        const u16* p; int ld;
        if (kcol < ka1) { p = a1 + (size_t)(m0 + (h << 7)) * lda1 + kcol;         ld = lda1; }
        else            { p = a2 + (size_t)(m0 + (h << 7)) * lda2 + (kcol - ka1); ld = lda2; }
        stage_ht(p, ld, sA + (((kt & 1) << 1) + h) * 8192, t);
    };
    auto stB = [&](int kt, int h) {
        stage_ht(bt + (size_t)(n0 + (h << 7)) * ldb + (kt << 6), ldb,
                 sB + (((kt & 1) << 1) + h) * 8192, t);
    };

    // prologue: ktile0 fully + Bh0(ktile1); leave 1 HT (2 loads) in flight
    stA(0, 0); stA(0, 1); stB(0, 0); stB(0, 1); stB(1, 0);
    VMCNT(2)
    BARR();

    f16x8 b[4];
    const int NI2 = K >> 7;
    const u16 *cA, *cB;
    for (int j = 0; j < NI2; ++j) {
        const int kA = 2 * j + 1, kB = 2 * j + 2, kC = 2 * j + 3;
        cA = A0; cB = B0;                       // ktile 2j (buf0)
        PHASE(0, ce0, true , stB(kA, 1), )
        PHASE(1, ce0, false, stA(kA, 0), )
        PHASE(0, ce1, true , stA(kA, 1), )
        PHASE(1, ce1, false, stB(kB, 0), VMCNT(2))
        cA = A1h; cB = B1h;                     // ktile 2j+1 (buf1)
        PHASE(0, ce0, true , stB(kB, 1), )
        PHASE(1, ce0, false, stA(kB, 0), )
        PHASE(0, ce1, true , stA(kB, 1), )
        PHASE(1, ce1, false, stB(kC, 0), VMCNT(2))
    }
    asm volatile("s_waitcnt vmcnt(0)" ::: "memory");   // drain dangling prefetch
}

#define EPI8                                        \
    const int lane = threadIdx.x & 63;              \
    const int wave = threadIdx.x >> 6;              \
    const int wm = wave >> 2;                       \
    const int wn = wave & 3;                        \
    const int lr = lane & 15;                       \
    const int l4 = (lane >> 4) << 2;

// mega-projection: C[8192 x 4096] = P @ Wio^T ; col = dir*2048 + e*512 + h
// write transposed: T[dir][b][h][e*256+m]
__global__ __launch_bounds__(512, 2) void k_proj(const u16* __restrict__ P,
                                                 const u16* __restrict__ Wio,
                                                 const float* __restrict__ b_in,
                                                 const float* __restrict__ b_out,
                                                 u16* __restrict__ T)
{
    __shared__ u16 sA[4 * 8192], sB[4 * 8192];
    const int fid = xcd_swz(blockIdx.x, gridDim.x);
    const int n = fid & 15, m = fid >> 4;
    const int m0 = m << 8, n0 = n << 8;
    f32x4 acc[8][4] = {};
    gemm256(P, 512, 512, P, 512, Wio, 512, 512, m0, n0, sA, sB, acc);
    EPI8
    #pragma unroll
    for (int fm = 0; fm < 8; ++fm) {
        const int row = m0 + (wm << 7) + fm * 16 + l4;
        const int b = row >> 8, mm = row & 255;
        #pragma unroll
        for (int fn = 0; fn < 4; ++fn) {
            const int col = n0 + (wn << 6) + fn * 16 + lr;
            const int dir = col >> 11, eh = col & 2047;
            const float bia = (dir ? b_out : b_in)[eh];
            const int e = eh >> 9, hh = eh & 511;
            ushort4 w4;
            w4.x = f2h(acc[fm][fn][0] + bia);
            w4.y = f2h(acc[fm][fn][1] + bia);
            w4.z = f2h(acc[fm][fn][2] + bia);
            w4.w = f2h(acc[fm][fn][3] + bia);
            *reinterpret_cast<ushort4*>(&T[(size_t)dir * TDIR + (size_t)b * 512 * 1024
                                           + (size_t)hh * 1024 + e * 256 + mm]) = w4;
        }
    }
}

// adjacency: per (b,dir): C[256x512] = A16[b][:, dir*1024:+1024] @ T[dir][b]^T
__global__ __launch_bounds__(512, 2) void k_amat(const u16* __restrict__ A16,
                                                 const u16* __restrict__ T,
                                                 u16* __restrict__ acat)
{
    __shared__ u16 sA[4 * 8192], sB[4 * 8192];
    const int fid = xcd_swz(blockIdx.x, gridDim.x);
    const int n = fid & 1, bd = fid >> 1;
    const int b = bd >> 1, dir = bd & 1;
    const int n0 = n << 8;
    const u16* A1 = A16 + (size_t)b * 256 * 2048 + dir * 1024;
    const u16* Bt = T + (size_t)dir * TDIR + (size_t)b * 512 * 1024;
    f32x4 acc[8][4] = {};
    gemm256(A1, 2048, 1024, A1, 2048, Bt, 1024, 1024, 0, n0, sA, sB, acc);
    EPI8
    #pragma unroll
    for (int fm = 0; fm < 8; ++fm) {
        const int row = (wm << 7) + fm * 16 + l4;
        #pragma unroll
        for (int fn = 0; fn < 4; ++fn) {
            const int col = n0 + (wn << 6) + fn * 16 + lr;
            #pragma unroll
            for (int v = 0; v < 4; ++v)
                acat[((size_t)b * 256 + row + v) * 1024 + dir * 512 + col] = f2h(acc[fm][fn][v]);
        }
    }
}

// gates: X[8192 x 1536] = [acat | P] @ Wrzh^T (h-block zero-padded over P rows)
// n0<512: rp = f16(sigmoid(X+br)*P) ; n0<1024: z = sigmoid(X+bz) ; else hpart = X
__global__ __launch_bounds__(512, 2) void k_gates(const u16* __restrict__ acat,
                                                  const u16* __restrict__ P,
                                                  const u16* __restrict__ Wrzh,
                                                  const float* __restrict__ br,
                                                  const float* __restrict__ bz,
                                                  u16* __restrict__ rp,
                                                  float* __restrict__ z,
                                                  float* __restrict__ hpart)
{
    __shared__ u16 sA[4 * 8192], sB[4 * 8192];
    const int fid = xcd_swz(blockIdx.x, gridDim.x);
    const int n = fid % 6, m = fid / 6;
    const int m0 = m << 8, n0 = n << 8;
    f32x4 acc[8][4] = {};
    gemm256(acat, 1024, 1024, P, 512, Wrzh, 1536, 1536, m0, n0, sA, sB, acc);
    EPI8
    #pragma unroll
    for (int fm = 0; fm < 8; ++fm) {
        const int row = m0 + (wm << 7) + fm * 16 + l4;
        #pragma unroll
        for (int fn = 0; fn < 4; ++fn) {
            const int col = n0 + (wn << 6) + fn * 16 + lr;
            if (n0 < 512) {
                const float bia = br[col];
                #pragma unroll
                for (int v = 0; v < 4; ++v) {
                    const float s = 1.0f / (1.0f + __expf(-(acc[fm][fn][v] + bia)));
                    const size_t idx = (size_t)(row + v) * 512 + col;
                    rp[idx] = f2h(s * h2f(P[idx]));
                }
            } else if (n0 < 1024) {
                const float bia = bz[col - 512];
                #pragma unroll
                for (int v = 0; v < 4; ++v)
                    z[(size_t)(row + v) * 512 + (col - 512)] =
                        1.0f / (1.0f + __expf(-(acc[fm][fn][v] + bia)));
            } else {
                #pragma unroll
                for (int v = 0; v < 4; ++v)
                    hpart[(size_t)(row + v) * 512 + (col - 1024)] = acc[fm][fn][v];
            }
        }
    }
}

// ======================= 2-phase 128x128 core (hup/final) =======================
static __device__ __forceinline__ void stage_tile(const u16* __restrict__ src, int ld,
                                                  u16* lds, int wave, int lane) {
    const int r = lane >> 2;
    const int c = (lane & 3) << 3;
    const u16* g0 = src + (size_t)(wave * 32 + r) * ld + c;
    GLL(g0, lds + wave * 1024);
    GLL(g0 + (size_t)16 * ld, lds + wave * 1024 + 512);
}

static __device__ __forceinline__ void compute32(const u16* lA, const u16* lB,
                                                 int wq_r, int wq_c, int lr, int lk,
                                                 f32x4 acc[4][4]) {
    f16x8 a[4], b[4];
    #pragma unroll
    for (int i = 0; i < 4; ++i)
        a[i] = *reinterpret_cast<const f16x8*>(&lA[(wq_r + i * 16 + lr) * 32 + lk]);
    #pragma unroll
    for (int j = 0; j < 4; ++j)
        b[j] = *reinterpret_cast<const f16x8*>(&lB[(wq_c + j * 16 + lr) * 32 + lk]);
    #pragma unroll
    for (int i = 0; i < 4; ++i)
        #pragma unroll
        for (int j = 0; j < 4; ++j)
            acc[i][j] = __builtin_amdgcn_mfma_f32_16x16x32_f16(a[i], b[j], acc[i][j], 0, 0, 0);
}

static __device__ __forceinline__ void gemm128(const u16* __restrict__ a1, int lda1, int ka1,
                                               const u16* __restrict__ a2, int lda2,
                                               const u16* __restrict__ bt, int ldb,
                                               int K, int m0, int n0,
                                               u16* sA, u16* sB, f32x4 acc[4][4])
{
    const int t = threadIdx.x, lane = t & 63, wave = t >> 6;
    const int lr = lane & 15, lk = (lane >> 4) << 3;
    const int wq_r = (wave >> 1) << 6, wq_c = (wave & 1) << 6;
    const int nt = K >> 5;
    stage_tile(a1 + (size_t)m0 * lda1, lda1, sA, wave, lane);
    stage_tile(bt + (size_t)n0 * ldb, ldb, sB, wave, lane);
    __syncthreads();
    int buf = 0;
    for (int ti = 0; ti < nt; ++ti) {
        const int k1 = (ti + 1) << 5;
        if (k1 < K) {
            const u16* s;
            int ld;
            if (k1 < ka1) { s = a1 + (size_t)m0 * lda1 + k1;         ld = lda1; }
            else          { s = a2 + (size_t)m0 * lda2 + (k1 - ka1); ld = lda2; }
            stage_tile(s, ld, sA + (buf ^ 1) * 4096, wave, lane);
            stage_tile(bt + (size_t)n0 * ldb + k1, ldb, sB + (buf ^ 1) * 4096, wave, lane);
        }
        compute32(sA + buf * 4096, sB + buf * 4096, wq_r, wq_c, lr, lk, acc);
        __syncthreads();
        buf ^= 1;
    }
}

#define EPI                                         \
    const int lane = threadIdx.x & 63;              \
    const int wave = threadIdx.x >> 6;              \
    const int wq_r = (wave >> 1) << 6;              \
    const int wq_c = (wave & 1) << 6;               \
    const int lr = lane & 15;                       \
    const int l4 = (lane >> 4) << 2;

// h/update: Y = rp @ WhP^T (K=512) ; h = tanh(hpart + Y + bh) ; P = (1-z)P + z h
__global__ __launch_bounds__(256, 4) void k_hup(const u16* __restrict__ rp,
                                                const u16* __restrict__ WhP,
                                                const float* __restrict__ bh,
                                                const float* __restrict__ z,
                                                const float* __restrict__ hpart,
                                                u16* __restrict__ P)
{
    __shared__ u16 sA[2 * 4096], sB[2 * 4096];
    const int fid = xcd_swz(blockIdx.x, gridDim.x);
    const int n = fid & 3, m = fid >> 2;
    const int m0 = m << 7, n0 = n << 7;
    f32x4 acc[4][4] = {};
    gemm128(rp, 512, 512, rp, 512, WhP, 512, 512, m0, n0, sA, sB, acc);
    EPI
    #pragma unroll
    for (int i = 0; i < 4; ++i) {
        const int row = m0 + wq_r + i * 16 + l4;
        #pragma unroll
        for (int j = 0; j < 4; ++j) {
            const int col = n0 + wq_c + j * 16 + lr;
            const float bia = bh[col];
            #pragma unroll
            for (int v = 0; v < 4; ++v) {
                const size_t idx = (size_t)(row + v) * 512 + col;
                const float hh = tanhf(hpart[idx] + acc[i][j][v] + bia);
                const float zz = z[idx];
                const float pn = (1.0f - zz) * h2f(P[idx]) + zz * hh;
                P[idx] = f2h(pn);
            }
        }
    }
}

// final: out = tanh([P | ann] @ Wj^T + bo) (f32)
__global__ __launch_bounds__(256, 4) void k_final(const u16* __restrict__ P,
                                                  const u16* __restrict__ annf,
                                                  const u16* __restrict__ Wj,
                                                  const float* __restrict__ bo,
                                                  float* __restrict__ out)
{
    __shared__ u16 sA[2 * 4096], sB[2 * 4096];
    const int fid = xcd_swz(blockIdx.x, gridDim.x);
    const int n = fid & 3, m = fid >> 2;
    const int m0 = m << 7, n0 = n << 7;
    f32x4 acc[4][4] = {};
    gemm128(P, 512, 512, annf, 256, Wj, 768, 768, m0, n0, sA, sB, acc);
    EPI
    #pragma unroll
    for (int i = 0; i < 4; ++i) {
        const int row = m0 + wq_r + i * 16 + l4;
        #pragma unroll
        for (int j = 0; j < 4; ++j) {
            const int col = n0 + wq_c + j * 16 + lr;
            const float bia = bo[col];
            #pragma unroll
            for (int v = 0; v < 4; ++v)
                out[(size_t)(row + v) * 512 + col] = tanhf(acc[i][j][v] + bia);
        }
    }
}

// ---- setup ----
__global__ void s_gather(const int* __restrict__ ann, const float* __restrict__ emb,
                         u16* __restrict__ P, u16* __restrict__ annf)
{
    const int gid = blockIdx.x * 256 + threadIdx.x;  // < 8192*512
    const int row = gid >> 9, d = gid & 511;
    float v = 0.0f;
    if (d < 256) v = emb[(size_t)ann[row] * 256 + d];
    const u16 h = f2h(v);
    P[gid] = h;
    if (d < 256) annf[((size_t)row << 8) + d] = h;
}

__global__ void s_cvtA(const float* __restrict__ src, u16* __restrict__ dst)
{
    const size_t base = ((size_t)blockIdx.x * 256 + threadIdx.x) * 8;  // < 8192*2048
    float4 f0 = *reinterpret_cast<const float4*>(src + base);
    float4 f1 = *reinterpret_cast<const float4*>(src + base + 4);
    ushort4 p0 = { f2h(f0.x), f2h(f0.y), f2h(f0.z), f2h(f0.w) };
    ushort4 p1 = { f2h(f1.x), f2h(f1.y), f2h(f1.z), f2h(f1.w) };
    *reinterpret_cast<ushort4*>(dst + base)     = p0;
    *reinterpret_cast<ushort4*>(dst + base + 4) = p1;
}

// Wio[n][k], n = dir*2048 + e*512 + h : = W_dir[e][k][h]
__global__ void s_wio(const float* __restrict__ Wi, const float* __restrict__ Wo,
                      u16* __restrict__ dst)
{
    const int gid = blockIdx.x * 256 + threadIdx.x;  // < 4096*512
    if (gid >= 4096 * 512) return;
    const int nn = gid >> 9, k = gid & 511;
    const int dir = nn >> 11, e = (nn >> 9) & 3, h = nn & 511;
    const float* W = dir ? Wo : Wi;
    dst[gid] = f2h(W[(size_t)e * 512 * 512 + (size_t)k * 512 + h]);
}

// Wrzh[n][k] (1536x1536): n<512 Wr[k][n]; n<1024 Wz[k][n-512]; else (k<1024 ? Wh[k][n-1024] : 0)
__global__ void s_wrzh(const float* __restrict__ Wr, const float* __restrict__ Wz,
                       const float* __restrict__ Wh, u16* __restrict__ dst)
{
    const int gid = blockIdx.x * 256 + threadIdx.x;  // < 1536*1536
    if (gid >= 1536 * 1536) return;
    const int nn = gid / 1536, k = gid - nn * 1536;
    float v;
    if (nn < 512)       v = Wr[(size_t)k * 512 + nn];
    else if (nn < 1024) v = Wz[(size_t)k * 512 + (nn - 512)];
    else                v = (k < 1024) ? Wh[(size_t)k * 512 + (nn - 1024)] : 0.0f;
    dst[gid] = f2h(v);
}

// WhP[n][k] (512x512): = Wh[1024+k][n]
__global__ void s_whp(const float* __restrict__ Wh, u16* __restrict__ dst)
{
    const int gid = blockIdx.x * 256 + threadIdx.x;  // < 512*512
    if (gid >= 512 * 512) return;
    const int nn = gid >> 9, k = gid & 511;
    dst[gid] = f2h(Wh[(size_t)(1024 + k) * 512 + nn]);
}

// Wj[n][k] (512x768): = Wo[k][n]
__global__ void s_wj(const float* __restrict__ Wo, u16* __restrict__ dst)
{
    const int gid = blockIdx.x * 256 + threadIdx.x;  // < 512*768
    if (gid >= 512 * 768) return;
    const int nn = gid / 768, k = gid - nn * 768;
    dst[gid] = f2h(Wo[(size_t)k * 512 + nn]);
}

extern "C" void kernel_launch(void* const* d_in, const int* in_sizes, int n_in,
                              void* d_out, int out_size, void* d_ws, size_t ws_size,
                              hipStream_t stream) {
    const int*   ann   = (const int*)d_in[0];
    const float* A     = (const float*)d_in[1];
    const float* emb   = (const float*)d_in[2];
    const float* W_in  = (const float*)d_in[3];
    const float* b_in  = (const float*)d_in[4];
    const float* W_out = (const float*)d_in[5];
    const float* b_out = (const float*)d_in[6];
    const float* Wr    = (const float*)d_in[7];
    const float* br    = (const float*)d_in[8];
    const float* Wz    = (const float*)d_in[9];
    const float* bz    = (const float*)d_in[10];
    const float* Wh    = (const float*)d_in[11];
    const float* bh    = (const float*)d_in[12];
    const float* Wo    = (const float*)d_in[13];
    const float* bo    = (const float*)d_in[14];
    float* out = (float*)d_out;

    char* ws = (char*)d_ws;
    size_t off = 0;
    auto alloc = [&](size_t bytes) -> void* {
        void* p = ws + off;
        off = (off + bytes + 255) & ~(size_t)255;
        return p;
    };
    // order matters: buffers read by gemm256 may be prefetch-overrun by up to
    // 256 B — each is followed by another allocation, never the ws end.
    float* z_f32 = (float*)alloc(8192ull * 512 * 4);   // 16 MB
    float* hpart = (float*)alloc(8192ull * 512 * 4);   // 16 MB
    u16* P     = (u16*)alloc(8192ull * 512 * 2);       // 8 MB
    u16* rp    = (u16*)alloc(8192ull * 512 * 2);       // 8 MB
    u16* annf  = (u16*)alloc(8192ull * 256 * 2);       // 4 MB
    u16* acat  = (u16*)alloc(8192ull * 1024 * 2);      // 16 MB
    u16* A16   = (u16*)alloc(8192ull * 2048 * 2);      // 32 MB
    u16* T     = (u16*)alloc(2 * TDIR * 2);            // 64 MB
    u16* WioT  = (u16*)alloc(4096ull * 512 * 2);       // 4 MB
    u16* WrzhT = (u16*)alloc(1536ull * 1536 * 2);      // 4.7 MB
    u16* WhPT  = (u16*)alloc(512ull * 512 * 2);        // 0.5 MB
    u16* WjT   = (u16*)alloc(512ull * 768 * 2);        // 0.8 MB (read exactly, last)
    // total ~174 MB

    s_gather<<<16384, 256, 0, stream>>>(ann, emb, P, annf);
    s_cvtA<<<8192, 256, 0, stream>>>(A, A16);
    s_wio<<<(4096 * 512 + 255) / 256, 256, 0, stream>>>(W_in, W_out, WioT);
    s_wrzh<<<(1536 * 1536 + 255) / 256, 256, 0, stream>>>(Wr, Wz, Wh, WrzhT);
    s_whp<<<(512 * 512 + 255) / 256, 256, 0, stream>>>(Wh, WhPT);
    s_wj<<<(512 * 768 + 255) / 256, 256, 0, stream>>>(Wo, WjT);

    for (int s = 0; s < 5; ++s) {
        k_proj<<<512, 512, 0, stream>>>(P, WioT, b_in, b_out, T);
        k_amat<<<128, 512, 0, stream>>>(A16, T, acat);
        k_gates<<<192, 512, 0, stream>>>(acat, P, WrzhT, br, bz, rp, z_f32, hpart);
        k_hup<<<256, 256, 0, stream>>>(rp, WhPT, bh, z_f32, hpart, P);
    }
    k_final<<<256, 256, 0, stream>>>(P, annf, WjT, bo, out);
}

// Round 8
// 1018.371 us; speedup vs baseline: 1.1206x; 1.1206x over previous
//
#include <hip/hip_runtime.h>
#include <hip/hip_bf16.h>
#include <cstdint>
#include <cstddef>

typedef unsigned short u16;
typedef _Float16 f16;
typedef f16 f16x8 __attribute__((ext_vector_type(8)));
typedef float f32x4 __attribute__((ext_vector_type(4)));

static __device__ __forceinline__ u16 f2h(float f) {
    f16 h = (f16)f;
    return *reinterpret_cast<u16*>(&h);
}
static __device__ __forceinline__ float h2f(u16 u) {
    f16 h = *reinterpret_cast<f16*>(&u);
    return (float)h;
}

// async global->LDS, 16B per lane; LDS dest = wave-uniform base + lane*16
#define GLL(g, l) __builtin_amdgcn_global_load_lds(                    \
    (const __attribute__((address_space(1))) void*)(g),                \
    (__attribute__((address_space(3))) void*)(l), 16, 0, 0)

// bijective XCD swizzle (all grids % 8 == 0)
static __device__ __forceinline__ int xcd_swz(int fid, int nwg) {
    const int q = nwg >> 3;
    return (fid & 7) * q + (fid >> 3);
}

#define TDIR (32ull * 512 * 1024)

// stage a 128x32 u16 tile (row-major src, ld elements) into linear lds[128*32]
static __device__ __forceinline__ void stage_tile(const u16* __restrict__ src, int ld,
                                                  u16* lds, int wave, int lane) {
    const int r = lane >> 2;
    const int c = (lane & 3) << 3;
    const u16* g0 = src + (size_t)(wave * 32 + r) * ld + c;
    GLL(g0, lds + wave * 1024);
    GLL(g0 + (size_t)16 * ld, lds + wave * 1024 + 512);
}

// stage a 64x32 u16 tile into linear lds[64*32] (1 GLL/thread, 256 threads)
static __device__ __forceinline__ void stage_tile64(const u16* __restrict__ src, int ld,
                                                    u16* lds, int t) {
    GLL(src + (size_t)(t >> 2) * ld + ((t & 3) << 3), lds + ((t >> 6) << 9));
}

// ---------------- 128x128 core (2-phase dbuf, 4 waves, 4x4 frags) ----------------
static __device__ __forceinline__ void compute32(const u16* lA, const u16* lB,
                                                 int wq_r, int wq_c, int lr, int lk,
                                                 f32x4 acc[4][4]) {
    f16x8 a[4], b[4];
    #pragma unroll
    for (int i = 0; i < 4; ++i)
        a[i] = *reinterpret_cast<const f16x8*>(&lA[(wq_r + i * 16 + lr) * 32 + lk]);
    #pragma unroll
    for (int j = 0; j < 4; ++j)
        b[j] = *reinterpret_cast<const f16x8*>(&lB[(wq_c + j * 16 + lr) * 32 + lk]);
    #pragma unroll
    for (int i = 0; i < 4; ++i)
        #pragma unroll
        for (int j = 0; j < 4; ++j)
            acc[i][j] = __builtin_amdgcn_mfma_f32_16x16x32_f16(a[i], b[j], acc[i][j], 0, 0, 0);
}

static __device__ __forceinline__ void gemm128(const u16* __restrict__ a1, int lda1, int ka1,
                                               const u16* __restrict__ a2, int lda2,
                                               const u16* __restrict__ bt, int ldb,
                                               int K, int m0, int n0,
                                               u16* sA, u16* sB, f32x4 acc[4][4])
{
    const int t = threadIdx.x, lane = t & 63, wave = t >> 6;
    const int lr = lane & 15, lk = (lane >> 4) << 3;
    const int wq_r = (wave >> 1) << 6, wq_c = (wave & 1) << 6;
    const int nt = K >> 5;
    stage_tile(a1 + (size_t)m0 * lda1, lda1, sA, wave, lane);
    stage_tile(bt + (size_t)n0 * ldb, ldb, sB, wave, lane);
    __syncthreads();
    int buf = 0;
    for (int ti = 0; ti < nt; ++ti) {
        const int k1 = (ti + 1) << 5;
        if (k1 < K) {
            const u16* s;
            int ld;
            if (k1 < ka1) { s = a1 + (size_t)m0 * lda1 + k1;         ld = lda1; }
            else          { s = a2 + (size_t)m0 * lda2 + (k1 - ka1); ld = lda2; }
            stage_tile(s, ld, sA + (buf ^ 1) * 4096, wave, lane);
            stage_tile(bt + (size_t)n0 * ldb + k1, ldb, sB + (buf ^ 1) * 4096, wave, lane);
        }
        compute32(sA + buf * 4096, sB + buf * 4096, wq_r, wq_c, lr, lk, acc);
        __syncthreads();
        buf ^= 1;
    }
}

// ---------------- 128x64 core (2-phase dbuf, 4 waves, wave = 32 rows x 64 cols) ----------------
static __device__ __forceinline__ void gemm12864(const u16* __restrict__ a1, int lda1, int ka1,
                                                 const u16* __restrict__ a2, int lda2,
                                                 const u16* __restrict__ bt, int ldb,
                                                 int K, int m0, int n0,
                                                 u16* sA, u16* sB, f32x4 acc[2][4])
{
    const int t = threadIdx.x, lane = t & 63, wave = t >> 6;
    const int lr = lane & 15, lk = (lane >> 4) << 3;
    const int wq_r = wave << 5;
    const int nt = K >> 5;
    stage_tile(a1 + (size_t)m0 * lda1, lda1, sA, wave, lane);
    stage_tile64(bt + (size_t)n0 * ldb, ldb, sB, t);
    __syncthreads();
    int buf = 0;
    for (int ti = 0; ti < nt; ++ti) {
        const int k1 = (ti + 1) << 5;
        if (k1 < K) {
            const u16* s;
            int ld;
            if (k1 < ka1) { s = a1 + (size_t)m0 * lda1 + k1;         ld = lda1; }
            else          { s = a2 + (size_t)m0 * lda2 + (k1 - ka1); ld = lda2; }
            stage_tile(s, ld, sA + (buf ^ 1) * 4096, wave, lane);
            stage_tile64(bt + (size_t)n0 * ldb + k1, ldb, sB + (buf ^ 1) * 2048, t);
        }
        const u16* lA = sA + buf * 4096;
        const u16* lB = sB + buf * 2048;
        f16x8 a[2], b[4];
        #pragma unroll
        for (int i = 0; i < 2; ++i)
            a[i] = *reinterpret_cast<const f16x8*>(&lA[(wq_r + i * 16 + lr) * 32 + lk]);
        #pragma unroll
        for (int j = 0; j < 4; ++j)
            b[j] = *reinterpret_cast<const f16x8*>(&lB[(j * 16 + lr) * 32 + lk]);
        #pragma unroll
        for (int i = 0; i < 2; ++i)
            #pragma unroll
            for (int j = 0; j < 4; ++j)
                acc[i][j] = __builtin_amdgcn_mfma_f32_16x16x32_f16(a[i], b[j], acc[i][j], 0, 0, 0);
        __syncthreads();
        buf ^= 1;
    }
}

#define EPI                                         \
    const int lane = threadIdx.x & 63;              \
    const int wave = threadIdx.x >> 6;              \
    const int wq_r = (wave >> 1) << 6;              \
    const int wq_c = (wave & 1) << 6;               \
    const int lr = lane & 15;                       \
    const int l4 = (lane >> 4) << 2;

#define EPI64                                       \
    const int lane = threadIdx.x & 63;              \
    const int wave = threadIdx.x >> 6;              \
    const int wq_r = wave << 5;                     \
    const int lr = lane & 15;                       \
    const int l4 = (lane >> 4) << 2;

// mega-projection: C[8192 x 4096] = P @ Wio^T ; col = dir*2048 + e*512 + h
// write transposed: T[dir][b][h][e*256+m]
__global__ __launch_bounds__(256, 4) void k_proj(const u16* __restrict__ P,
                                                 const u16* __restrict__ Wio,
                                                 const float* __restrict__ b_in,
                                                 const float* __restrict__ b_out,
                                                 u16* __restrict__ T)
{
    __shared__ u16 sA[2 * 4096], sB[2 * 4096];
    const int fid = xcd_swz(blockIdx.x, gridDim.x);
    const int n = fid & 31, m = fid >> 5;
    const int m0 = m << 7, n0 = n << 7;
    f32x4 acc[4][4] = {};
    gemm128(P, 512, 512, P, 512, Wio, 512, 512, m0, n0, sA, sB, acc);
    EPI
    #pragma unroll
    for (int i = 0; i < 4; ++i) {
        const int row = m0 + wq_r + i * 16 + l4;
        const int b = row >> 8, mm = row & 255;
        #pragma unroll
        for (int j = 0; j < 4; ++j) {
            const int col = n0 + wq_c + j * 16 + lr;
            const int dir = col >> 11, eh = col & 2047;
            const float bia = (dir ? b_out : b_in)[eh];
            const int e = eh >> 9, hh = eh & 511;
            ushort4 w4;
            w4.x = f2h(acc[i][j][0] + bia);
            w4.y = f2h(acc[i][j][1] + bia);
            w4.z = f2h(acc[i][j][2] + bia);
            w4.w = f2h(acc[i][j][3] + bia);
            *reinterpret_cast<ushort4*>(&T[(size_t)dir * TDIR + (size_t)b * 512 * 1024
                                           + (size_t)hh * 1024 + e * 256 + mm]) = w4;
        }
    }
}

// adjacency: per (b,dir): C[256x512] = A16[b][:, dir*1024:+1024] @ T[dir][b]^T (64-col tiles)
__global__ __launch_bounds__(256, 4) void k_amat(const u16* __restrict__ A16,
                                                 const u16* __restrict__ T,
                                                 u16* __restrict__ acat)
{
    __shared__ u16 sA[2 * 4096], sB[2 * 2048];
    const int fid = xcd_swz(blockIdx.x, gridDim.x);
    const int n = fid & 7, m = (fid >> 3) & 1, bd = fid >> 4;
    const int b = bd >> 1, dir = bd & 1;
    const int m0 = m << 7, n0 = n << 6;
    const u16* A1 = A16 + (size_t)b * 256 * 2048 + dir * 1024;
    const u16* Bt = T + (size_t)dir * TDIR + (size_t)b * 512 * 1024;
    f32x4 acc[2][4] = {};
    gemm12864(A1, 2048, 1024, A1, 2048, Bt, 1024, 1024, m0, n0, sA, sB, acc);
    EPI64
    #pragma unroll
    for (int i = 0; i < 2; ++i) {
        const int row = m0 + wq_r + i * 16 + l4;
        #pragma unroll
        for (int j = 0; j < 4; ++j) {
            const int col = n0 + j * 16 + lr;
            #pragma unroll
            for (int v = 0; v < 4; ++v)
                acat[((size_t)b * 256 + row + v) * 1024 + dir * 512 + col] = f2h(acc[i][j][v]);
        }
    }
}

// gates: X[8192 x 1536] = [acat | P] @ Wrzh^T (h-block zero-padded over P rows), 64-col tiles
// n0<512: rp = f16(sigmoid(X+br)*P) ; n0<1024: z16 = f16 sigmoid ; else hp16 = f16 X
__global__ __launch_bounds__(256, 4) void k_gates(const u16* __restrict__ acat,
                                                  const u16* __restrict__ P,
                                                  const u16* __restrict__ Wrzh,
                                                  const float* __restrict__ br,
                                                  const float* __restrict__ bz,
                                                  u16* __restrict__ rp,
                                                  u16* __restrict__ z16,
                                                  u16* __restrict__ hp16)
{
    __shared__ u16 sA[2 * 4096], sB[2 * 2048];
    const int fid = xcd_swz(blockIdx.x, gridDim.x);
    const int n = fid % 24, m = fid / 24;
    const int m0 = m << 7, n0 = n << 6;
    f32x4 acc[2][4] = {};
    gemm12864(acat, 1024, 1024, P, 512, Wrzh, 1536, 1536, m0, n0, sA, sB, acc);
    EPI64
    #pragma unroll
    for (int i = 0; i < 2; ++i) {
        const int row = m0 + wq_r + i * 16 + l4;
        #pragma unroll
        for (int j = 0; j < 4; ++j) {
            const int col = n0 + j * 16 + lr;
            if (n0 < 512) {
                const float bia = br[col];
                #pragma unroll
                for (int v = 0; v < 4; ++v) {
                    const float s = 1.0f / (1.0f + __expf(-(acc[i][j][v] + bia)));
                    const size_t idx = (size_t)(row + v) * 512 + col;
                    rp[idx] = f2h(s * h2f(P[idx]));
                }
            } else if (n0 < 1024) {
                const float bia = bz[col - 512];
                #pragma unroll
                for (int v = 0; v < 4; ++v)
                    z16[(size_t)(row + v) * 512 + (col - 512)] =
                        f2h(1.0f / (1.0f + __expf(-(acc[i][j][v] + bia))));
            } else {
                #pragma unroll
                for (int v = 0; v < 4; ++v)
                    hp16[(size_t)(row + v) * 512 + (col - 1024)] = f2h(acc[i][j][v]);
            }
        }
    }
}

// h/update: Y = rp @ WhP^T (K=512) ; h = tanh(hp + Y + bh) ; P = (1-z)P + z h  (64-col tiles)
__global__ __launch_bounds__(256, 4) void k_hup(const u16* __restrict__ rp,
                                                const u16* __restrict__ WhP,
                                                const float* __restrict__ bh,
                                                const u16* __restrict__ z16,
                                                const u16* __restrict__ hp16,
                                                u16* __restrict__ P)
{
    __shared__ u16 sA[2 * 4096], sB[2 * 2048];
    const int fid = xcd_swz(blockIdx.x, gridDim.x);
    const int n = fid & 7, m = fid >> 3;
    const int m0 = m << 7, n0 = n << 6;
    f32x4 acc[2][4] = {};
    gemm12864(rp, 512, 512, rp, 512, WhP, 512, 512, m0, n0, sA, sB, acc);
    EPI64
    #pragma unroll
    for (int i = 0; i < 2; ++i) {
        const int row = m0 + wq_r + i * 16 + l4;
        #pragma unroll
        for (int j = 0; j < 4; ++j) {
            const int col = n0 + j * 16 + lr;
            const float bia = bh[col];
            #pragma unroll
            for (int v = 0; v < 4; ++v) {
                const size_t idx = (size_t)(row + v) * 512 + col;
                const float hh = tanhf(h2f(hp16[idx]) + acc[i][j][v] + bia);
                const float zz = h2f(z16[idx]);
                const float pn = (1.0f - zz) * h2f(P[idx]) + zz * hh;
                P[idx] = f2h(pn);
            }
        }
    }
}

// final: out = tanh([P | ann] @ Wj^T + bo) (f32)
__global__ __launch_bounds__(256, 4) void k_final(const u16* __restrict__ P,
                                                  const u16* __restrict__ annf,
                                                  const u16* __restrict__ Wj,
                                                  const float* __restrict__ bo,
                                                  float* __restrict__ out)
{
    __shared__ u16 sA[2 * 4096], sB[2 * 4096];
    const int fid = xcd_swz(blockIdx.x, gridDim.x);
    const int n = fid & 3, m = fid >> 2;
    const int m0 = m << 7, n0 = n << 7;
    f32x4 acc[4][4] = {};
    gemm128(P, 512, 512, annf, 256, Wj, 768, 768, m0, n0, sA, sB, acc);
    EPI
    #pragma unroll
    for (int i = 0; i < 4; ++i) {
        const int row = m0 + wq_r + i * 16 + l4;
        #pragma unroll
        for (int j = 0; j < 4; ++j) {
            const int col = n0 + wq_c + j * 16 + lr;
            const float bia = bo[col];
            #pragma unroll
            for (int v = 0; v < 4; ++v)
                out[(size_t)(row + v) * 512 + col] = tanhf(acc[i][j][v] + bia);
        }
    }
}

// ---- setup ----
__global__ void s_gather(const int* __restrict__ ann, const float* __restrict__ emb,
                         u16* __restrict__ P, u16* __restrict__ annf)
{
    const int gid = blockIdx.x * 256 + threadIdx.x;  // < 8192*512
    const int row = gid >> 9, d = gid & 511;
    float v = 0.0f;
    if (d < 256) v = emb[(size_t)ann[row] * 256 + d];
    const u16 h = f2h(v);
    P[gid] = h;
    if (d < 256) annf[((size_t)row << 8) + d] = h;
}

__global__ void s_cvtA(const float* __restrict__ src, u16* __restrict__ dst)
{
    const size_t base = ((size_t)blockIdx.x * 256 + threadIdx.x) * 8;  // < 8192*2048
    float4 f0 = *reinterpret_cast<const float4*>(src + base);
    float4 f1 = *reinterpret_cast<const float4*>(src + base + 4);
    ushort4 p0 = { f2h(f0.x), f2h(f0.y), f2h(f0.z), f2h(f0.w) };
    ushort4 p1 = { f2h(f1.x), f2h(f1.y), f2h(f1.z), f2h(f1.w) };
    *reinterpret_cast<ushort4*>(dst + base)     = p0;
    *reinterpret_cast<ushort4*>(dst + base + 4) = p1;
}

// Wio[n][k], n = dir*2048 + e*512 + h : = W_dir[e][k][h]
__global__ void s_wio(const float* __restrict__ Wi, const float* __restrict__ Wo,
                      u16* __restrict__ dst)
{
    const int gid = blockIdx.x * 256 + threadIdx.x;  // < 4096*512
    if (gid >= 4096 * 512) return;
    const int nn = gid >> 9, k = gid & 511;
    const int dir = nn >> 11, e = (nn >> 9) & 3, h = nn & 511;
    const float* W = dir ? Wo : Wi;
    dst[gid] = f2h(W[(size_t)e * 512 * 512 + (size_t)k * 512 + h]);
}

// Wrzh[n][k] (1536x1536): n<512 Wr[k][n]; n<1024 Wz[k][n-512]; else (k<1024 ? Wh[k][n-1024] : 0)
__global__ void s_wrzh(const float* __restrict__ Wr, const float* __restrict__ Wz,
                       const float* __restrict__ Wh, u16* __restrict__ dst)
{
    const int gid = blockIdx.x * 256 + threadIdx.x;  // < 1536*1536
    if (gid >= 1536 * 1536) return;
    const int nn = gid / 1536, k = gid - nn * 1536;
    float v;
    if (nn < 512)       v = Wr[(size_t)k * 512 + nn];
    else if (nn < 1024) v = Wz[(size_t)k * 512 + (nn - 512)];
    else                v = (k < 1024) ? Wh[(size_t)k * 512 + (nn - 1024)] : 0.0f;
    dst[gid] = f2h(v);
}

// WhP[n][k] (512x512): = Wh[1024+k][n]
__global__ void s_whp(const float* __restrict__ Wh, u16* __restrict__ dst)
{
    const int gid = blockIdx.x * 256 + threadIdx.x;  // < 512*512
    if (gid >= 512 * 512) return;
    const int nn = gid >> 9, k = gid & 511;
    dst[gid] = f2h(Wh[(size_t)(1024 + k) * 512 + nn]);
}

// Wj[n][k] (512x768): = Wo[k][n]
__global__ void s_wj(const float* __restrict__ Wo, u16* __restrict__ dst)
{
    const int gid = blockIdx.x * 256 + threadIdx.x;  // < 512*768
    if (gid >= 512 * 768) return;
    const int nn = gid / 768, k = gid - nn * 768;
    dst[gid] = f2h(Wo[(size_t)k * 512 + nn]);
}

extern "C" void kernel_launch(void* const* d_in, const int* in_sizes, int n_in,
                              void* d_out, int out_size, void* d_ws, size_t ws_size,
                              hipStream_t stream) {
    const int*   ann   = (const int*)d_in[0];
    const float* A     = (const float*)d_in[1];
    const float* emb   = (const float*)d_in[2];
    const float* W_in  = (const float*)d_in[3];
    const float* b_in  = (const float*)d_in[4];
    const float* W_out = (const float*)d_in[5];
    const float* b_out = (const float*)d_in[6];
    const float* Wr    = (const float*)d_in[7];
    const float* br    = (const float*)d_in[8];
    const float* Wz    = (const float*)d_in[9];
    const float* bz    = (const float*)d_in[10];
    const float* Wh    = (const float*)d_in[11];
    const float* bh    = (const float*)d_in[12];
    const float* Wo    = (const float*)d_in[13];
    const float* bo    = (const float*)d_in[14];
    float* out = (float*)d_out;

    char* ws = (char*)d_ws;
    size_t off = 0;
    auto alloc = [&](size_t bytes) -> void* {
        void* p = ws + off;
        off = (off + bytes + 255) & ~(size_t)255;
        return p;
    };
    u16* z16   = (u16*)alloc(8192ull * 512 * 2);       // 8 MB
    u16* hp16  = (u16*)alloc(8192ull * 512 * 2);       // 8 MB
    u16* P     = (u16*)alloc(8192ull * 512 * 2);       // 8 MB
    u16* rp    = (u16*)alloc(8192ull * 512 * 2);       // 8 MB
    u16* annf  = (u16*)alloc(8192ull * 256 * 2);       // 4 MB
    u16* acat  = (u16*)alloc(8192ull * 1024 * 2);      // 16 MB
    u16* A16   = (u16*)alloc(8192ull * 2048 * 2);      // 32 MB
    u16* T     = (u16*)alloc(2 * TDIR * 2);            // 64 MB
    u16* WioT  = (u16*)alloc(4096ull * 512 * 2);       // 4 MB
    u16* WrzhT = (u16*)alloc(1536ull * 1536 * 2);      // 4.7 MB
    u16* WhPT  = (u16*)alloc(512ull * 512 * 2);        // 0.5 MB
    u16* WjT   = (u16*)alloc(512ull * 768 * 2);        // 0.8 MB
    // total ~158 MB

    s_gather<<<16384, 256, 0, stream>>>(ann, emb, P, annf);
    s_cvtA<<<8192, 256, 0, stream>>>(A, A16);
    s_wio<<<(4096 * 512 + 255) / 256, 256, 0, stream>>>(W_in, W_out, WioT);
    s_wrzh<<<(1536 * 1536 + 255) / 256, 256, 0, stream>>>(Wr, Wz, Wh, WrzhT);
    s_whp<<<(512 * 512 + 255) / 256, 256, 0, stream>>>(Wh, WhPT);
    s_wj<<<(512 * 768 + 255) / 256, 256, 0, stream>>>(Wo, WjT);

    for (int s = 0; s < 5; ++s) {
        k_proj<<<2048, 256, 0, stream>>>(P, WioT, b_in, b_out, T);
        k_amat<<<1024, 256, 0, stream>>>(A16, T, acat);
        k_gates<<<1536, 256, 0, stream>>>(acat, P, WrzhT, br, bz, rp, z16, hp16);
        k_hup<<<512, 256, 0, stream>>>(rp, WhPT, bh, z16, hp16, P);
    }
    k_final<<<256, 256, 0, stream>>>(P, annf, WjT, bo, out);
}